// Round 1
// baseline (885.365 us; speedup 1.0000x reference)
//
#include <hip/hip_runtime.h>

#define BATCH 8

__global__ void fill_one_kernel(float* __restrict__ out, int n) {
    int i = blockIdx.x * blockDim.x + threadIdx.x;
    if (i < n) out[i] = 1.0f;
}

__global__ void deg_kernel(const float* __restrict__ gea,
                           const int* __restrict__ ei0,
                           float* __restrict__ deg, int E) {
    int e = blockIdx.x * blockDim.x + threadIdx.x;
    if (e < E) atomicAdd(&deg[ei0[e]], gea[e]);
}

__global__ void edge_kernel(const float* __restrict__ y,
                            const float* __restrict__ dw,
                            const int* __restrict__ ei0,
                            const int* __restrict__ ei1,
                            const float* __restrict__ deg,
                            float* __restrict__ out,
                            int E, int N) {
    int e = blockIdx.x * blockDim.x + threadIdx.x;
    if (e >= E) return;
    int s0 = ei0[e];
    int s1 = ei1[e];
    float d = deg[s0];
    float inv = 1.0f / (d * d);               // deg^ALPHA, ALPHA=2
    float w = dw[e];
    float sig = 1.0f / (1.0f + __expf(-w));   // sigmoid
    float coef = sqrtf(sig) * inv;            // sqrt(edge_attr)/deg^2
#pragma unroll
    for (int b = 0; b < BATCH; ++b) {
        float y0 = y[b * N + s0];
        float y1 = y[b * N + s1];
        float gm = coef * fmaxf(y0 - y1, 0.0f);   // == |grad_m| (always >= 0)
        if (gm != 0.0f) atomicAdd(&out[b * N + s0], -gm);
    }
}

extern "C" void kernel_launch(void* const* d_in, const int* in_sizes, int n_in,
                              void* d_out, int out_size, void* d_ws, size_t ws_size,
                              hipStream_t stream) {
    const float* y   = (const float*)d_in[0];   // [B,N]
    // d_in[1] = t (unused)
    const float* gea = (const float*)d_in[2];   // [E]
    const float* dw  = (const float*)d_in[3];   // [E]
    const int*   ei  = (const int*)d_in[4];     // [2,E]

    const int E = in_sizes[2];
    const int N = in_sizes[0] / BATCH;

    const int* ei0 = ei;
    const int* ei1 = ei + E;

    float* deg = (float*)d_ws;                  // N floats of scratch

    // zero the degree accumulator (d_ws is poisoned before every call)
    hipMemsetAsync(deg, 0, (size_t)N * sizeof(float), stream);

    // out = 1.0 everywhere; edge contributions subtract from it
    {
        int n = out_size;
        fill_one_kernel<<<(n + 255) / 256, 256, 0, stream>>>((float*)d_out, n);
    }

    deg_kernel<<<(E + 255) / 256, 256, 0, stream>>>(gea, ei0, deg, E);

    edge_kernel<<<(E + 255) / 256, 256, 0, stream>>>(
        y, dw, ei0, ei1, deg, (float*)d_out, E, N);
}

// Round 2
// 444.757 us; speedup vs baseline: 1.9907x; 1.9907x over previous
//
#include <hip/hip_runtime.h>

#define BATCH 8
#define S_LOG 6
#define SBUCKET 64          // nodes per bucket
#define KMAX 1600           // max buckets (N up to 102400)
#define CB 256              // blocks for count/scatter passes
#define CTH 256

static inline size_t alignup(size_t x) { return (x + 255) & ~(size_t)255; }

// ---------------- pipeline kernels ----------------

__global__ void transpose_y(const float* __restrict__ y, float* __restrict__ yT, int N) {
    int n = blockIdx.x * blockDim.x + threadIdx.x;
    if (n < N) {
        float v[BATCH];
#pragma unroll
        for (int b = 0; b < BATCH; ++b) v[b] = y[(size_t)b * N + n];
        float4* dst = (float4*)(yT + (size_t)n * BATCH);
        dst[0] = make_float4(v[0], v[1], v[2], v[3]);
        dst[1] = make_float4(v[4], v[5], v[6], v[7]);
    }
}

__global__ void count_kernel(const int* __restrict__ ei0,
                             unsigned* __restrict__ counts, int E, int K) {
    __shared__ unsigned cnt[KMAX];
    for (int k = threadIdx.x; k < K; k += blockDim.x) cnt[k] = 0;
    __syncthreads();
    int chunk = (E + CB - 1) / CB;
    int lo = blockIdx.x * chunk;
    int hi = min(lo + chunk, E);
    for (int i = lo + threadIdx.x; i < hi; i += blockDim.x) {
        int k = ei0[i] >> S_LOG;
        atomicAdd(&cnt[k], 1u);
    }
    __syncthreads();
    for (int k = threadIdx.x; k < K; k += blockDim.x)
        counts[(size_t)blockIdx.x * K + k] = cnt[k];
}

// single block: bucket bases (bb) + per-(block,bucket) bases
__global__ void scan_kernel(const unsigned* __restrict__ counts,
                            unsigned* __restrict__ base,
                            unsigned* __restrict__ bb, int E, int K) {
    __shared__ unsigned tot[KMAX];
    __shared__ unsigned segsum[64];
    int tid = threadIdx.x;
    // bucket totals
    for (int k = tid; k < K; k += blockDim.x) {
        unsigned t = 0;
#pragma unroll 8
        for (int b = 0; b < CB; ++b) t += counts[(size_t)b * K + k];
        tot[k] = t;
    }
    __syncthreads();
    int seglen = (K + 63) >> 6;
    if (tid < 64) {
        unsigned run = 0;
        for (int j = 0; j < seglen; ++j) {
            int idx = tid * seglen + j;
            if (idx < K) { unsigned v = tot[idx]; tot[idx] = run; run += v; }
        }
        segsum[tid] = run;
    }
    __syncthreads();
    if (tid == 0) {
        unsigned run = 0;
        for (int s = 0; s < 64; ++s) { unsigned v = segsum[s]; segsum[s] = run; run += v; }
    }
    __syncthreads();
    for (int k = tid; k < K; k += blockDim.x) {
        unsigned v = tot[k] + segsum[k / seglen];
        tot[k] = v;
        bb[k] = v;
    }
    if (tid == 0) bb[K] = (unsigned)E;
    __syncthreads();
    // per-(block,bucket) base: exclusive prefix over blocks for each bucket
    for (int k = tid; k < K; k += blockDim.x) {
        unsigned run = tot[k];
#pragma unroll 8
        for (int b = 0; b < CB; ++b) {
            size_t idx = (size_t)b * K + k;
            unsigned c = counts[idx];
            base[idx] = run;
            run += c;
        }
    }
}

__global__ void scatter_kernel(const int* __restrict__ ei0, const int* __restrict__ ei1,
                               const float* __restrict__ dw, const float* __restrict__ gea,
                               const unsigned* __restrict__ base,
                               unsigned* __restrict__ packed,
                               float* __restrict__ coef0,
                               float* __restrict__ geab, int E, int K) {
    __shared__ unsigned cursor[KMAX];
    for (int k = threadIdx.x; k < K; k += blockDim.x)
        cursor[k] = base[(size_t)blockIdx.x * K + k];
    __syncthreads();
    int chunk = (E + CB - 1) / CB;
    int lo = blockIdx.x * chunk;
    int hi = min(lo + chunk, E);
    for (int i = lo + threadIdx.x; i < hi; i += blockDim.x) {
        int s0 = ei0[i];
        int s1 = ei1[i];
        int k = s0 >> S_LOG;
        unsigned s0l = (unsigned)(s0 & (SBUCKET - 1));
        unsigned pos = atomicAdd(&cursor[k], 1u);
        float w = dw[i];
        float sig = 1.0f / (1.0f + __expf(-w));
        packed[pos] = (unsigned)s1 | (s0l << 17);
        coef0[pos] = sqrtf(sig);
        geab[pos] = gea[i];
    }
}

__global__ __launch_bounds__(256)
void accum_kernel(const unsigned* __restrict__ packed,
                  const float* __restrict__ coef0,
                  const float* __restrict__ geab,
                  const unsigned* __restrict__ bb,
                  const float* __restrict__ yT,
                  float* __restrict__ out, int N) {
    __shared__ float degl[SBUCKET];
    __shared__ float invd2[SBUCKET];
    __shared__ float y0l[BATCH][SBUCKET];
    __shared__ float outl[BATCH][SBUCKET];
    int k = blockIdx.x;
    int n0 = k << S_LOG;
    int tid = threadIdx.x;

    for (int i = tid; i < SBUCKET; i += blockDim.x) degl[i] = 0.0f;
    for (int i = tid; i < BATCH * SBUCKET; i += blockDim.x) ((float*)outl)[i] = 0.0f;
    // preload this bucket's y0 values from yT (contiguous)
    int nvalid = min(SBUCKET, N - n0);          // nodes in this bucket
    for (int i = tid; i < nvalid * BATCH; i += blockDim.x) {
        int j = i >> 3;            // local node
        int b = i & 7;             // batch
        y0l[b][j] = yT[(size_t)n0 * BATCH + i];
    }
    unsigned lo = bb[k], hi = bb[k + 1];
    __syncthreads();

    for (unsigned r = lo + tid; r < hi; r += blockDim.x)
        atomicAdd(&degl[packed[r] >> 17], geab[r]);
    __syncthreads();

    for (int i = tid; i < SBUCKET; i += blockDim.x) {
        float d = degl[i];
        invd2[i] = 1.0f / (d * d);
    }
    __syncthreads();

    const float4* yt4 = (const float4*)yT;
    for (unsigned r = lo + tid; r < hi; r += blockDim.x) {
        unsigned p = packed[r];
        unsigned s1 = p & 0x1FFFFu;
        unsigned s0l = p >> 17;
        float c = coef0[r] * invd2[s0l];
        float4 ya = yt4[2 * (size_t)s1];
        float4 yb = yt4[2 * (size_t)s1 + 1];
        float y1v[BATCH] = {ya.x, ya.y, ya.z, ya.w, yb.x, yb.y, yb.z, yb.w};
#pragma unroll
        for (int b = 0; b < BATCH; ++b) {
            float gm = c * fmaxf(y0l[b][s0l] - y1v[b], 0.0f);
            if (gm != 0.0f) atomicAdd(&outl[b][s0l], gm);
        }
    }
    __syncthreads();

    for (int i = tid; i < BATCH * SBUCKET; i += blockDim.x) {
        int b = i >> S_LOG;
        int j = i & (SBUCKET - 1);
        int node = n0 + j;
        if (node < N) out[(size_t)b * N + node] = 1.0f - outl[b][j];
    }
}

// ---------------- fallback (R1 path) ----------------

__global__ void fill_one_kernel(float* __restrict__ out, int n) {
    int i = blockIdx.x * blockDim.x + threadIdx.x;
    if (i < n) out[i] = 1.0f;
}

__global__ void deg_kernel(const float* __restrict__ gea,
                           const int* __restrict__ ei0,
                           float* __restrict__ deg, int E) {
    int e = blockIdx.x * blockDim.x + threadIdx.x;
    if (e < E) atomicAdd(&deg[ei0[e]], gea[e]);
}

__global__ void edge_kernel(const float* __restrict__ y,
                            const float* __restrict__ dw,
                            const int* __restrict__ ei0,
                            const int* __restrict__ ei1,
                            const float* __restrict__ deg,
                            float* __restrict__ out,
                            int E, int N) {
    int e = blockIdx.x * blockDim.x + threadIdx.x;
    if (e >= E) return;
    int s0 = ei0[e];
    int s1 = ei1[e];
    float d = deg[s0];
    float inv = 1.0f / (d * d);
    float sig = 1.0f / (1.0f + __expf(-dw[e]));
    float coef = sqrtf(sig) * inv;
#pragma unroll
    for (int b = 0; b < BATCH; ++b) {
        float y0 = y[(size_t)b * N + s0];
        float y1 = y[(size_t)b * N + s1];
        float gm = coef * fmaxf(y0 - y1, 0.0f);
        if (gm != 0.0f) atomicAdd(&out[(size_t)b * N + s0], -gm);
    }
}

// ---------------- launch ----------------

extern "C" void kernel_launch(void* const* d_in, const int* in_sizes, int n_in,
                              void* d_out, int out_size, void* d_ws, size_t ws_size,
                              hipStream_t stream) {
    const float* y   = (const float*)d_in[0];   // [B,N]
    const float* gea = (const float*)d_in[2];   // [E]
    const float* dw  = (const float*)d_in[3];   // [E]
    const int*   ei  = (const int*)d_in[4];     // [2,E]

    const int E = in_sizes[2];
    const int N = in_sizes[0] / BATCH;
    const int* ei0 = ei;
    const int* ei1 = ei + E;

    const int K = (N + SBUCKET - 1) >> S_LOG;

    size_t o_yT     = 0;
    size_t o_packed = o_yT     + alignup((size_t)N * BATCH * 4);
    size_t o_coef   = o_packed + alignup((size_t)E * 4);
    size_t o_gea    = o_coef   + alignup((size_t)E * 4);
    size_t o_counts = o_gea    + alignup((size_t)E * 4);
    size_t o_base   = o_counts + alignup((size_t)CB * K * 4);
    size_t o_bb     = o_base   + alignup((size_t)CB * K * 4);
    size_t need     = o_bb     + alignup((size_t)(K + 1) * 4);

    if (K <= KMAX && N < (1 << 17) && ws_size >= need) {
        char* w = (char*)d_ws;
        float*    yT     = (float*)(w + o_yT);
        unsigned* packed = (unsigned*)(w + o_packed);
        float*    coef0  = (float*)(w + o_coef);
        float*    geab   = (float*)(w + o_gea);
        unsigned* counts = (unsigned*)(w + o_counts);
        unsigned* base   = (unsigned*)(w + o_base);
        unsigned* bb     = (unsigned*)(w + o_bb);

        transpose_y<<<(N + 255) / 256, 256, 0, stream>>>(y, yT, N);
        count_kernel<<<CB, CTH, 0, stream>>>(ei0, counts, E, K);
        scan_kernel<<<1, 1024, 0, stream>>>(counts, base, bb, E, K);
        scatter_kernel<<<CB, CTH, 0, stream>>>(ei0, ei1, dw, gea, base,
                                               packed, coef0, geab, E, K);
        accum_kernel<<<K, 256, 0, stream>>>(packed, coef0, geab, bb, yT,
                                            (float*)d_out, N);
    } else {
        // fallback: global-atomic path (needs only N floats of ws)
        float* deg = (float*)d_ws;
        hipMemsetAsync(deg, 0, (size_t)N * sizeof(float), stream);
        fill_one_kernel<<<(out_size + 255) / 256, 256, 0, stream>>>((float*)d_out, out_size);
        deg_kernel<<<(E + 255) / 256, 256, 0, stream>>>(gea, ei0, deg, E);
        edge_kernel<<<(E + 255) / 256, 256, 0, stream>>>(y, dw, ei0, ei1, deg,
                                                         (float*)d_out, E, N);
    }
}

// Round 3
// 279.915 us; speedup vs baseline: 3.1630x; 1.5889x over previous
//
#include <hip/hip_runtime.h>

#define BATCH 8
#define S_LOG 9
#define SBUCKET 512          // nodes per bucket
#define KC 256               // max buckets (N <= 131071)
#define CB 512               // blocks for count/scatter
#define TTILE 2048           // edges per sort tile
#define EPT (TTILE / 256)    // edges per thread per tile
#define MD 8                 // deg sub-blocks per bucket
#define MA 8                 // accum sub-blocks per bucket

static inline size_t alignup(size_t x) { return (x + 255) & ~(size_t)255; }

// ---------------- pipeline kernels ----------------

__global__ void transpose_y(const float* __restrict__ y, float* __restrict__ yT, int N) {
    int n = blockIdx.x * blockDim.x + threadIdx.x;
    if (n < N) {
        float v[BATCH];
#pragma unroll
        for (int b = 0; b < BATCH; ++b) v[b] = y[(size_t)b * N + n];
        float4* dst = (float4*)(yT + (size_t)n * BATCH);
        dst[0] = make_float4(v[0], v[1], v[2], v[3]);
        dst[1] = make_float4(v[4], v[5], v[6], v[7]);
    }
}

__global__ void count_kernel(const int* __restrict__ ei0,
                             unsigned* __restrict__ counts, int E) {
    __shared__ unsigned cnt[KC];
    int tid = threadIdx.x;
    cnt[tid] = 0;
    __syncthreads();
    int chunk = (E + CB - 1) / CB;
    int lo = blockIdx.x * chunk;
    int hi = min(lo + chunk, E);
    for (int i = lo + tid; i < hi; i += 256)
        atomicAdd(&cnt[ei0[i] >> S_LOG], 1u);
    __syncthreads();
    counts[(size_t)blockIdx.x * KC + tid] = cnt[tid];   // coalesced
}

// one block, 256 threads: thread t owns bucket t
__global__ void scan_kernel(const unsigned* __restrict__ counts,
                            unsigned* __restrict__ base,
                            unsigned* __restrict__ bb, int E) {
    __shared__ unsigned sb[KC];
    int t = threadIdx.x;
    unsigned tot = 0;
    for (int b = 0; b < CB; ++b) tot += counts[(size_t)b * KC + t];  // coalesced
    sb[t] = tot;
    __syncthreads();
    // inclusive Hillis-Steele scan over 256
    for (int off = 1; off < KC; off <<= 1) {
        unsigned u = sb[t];
        unsigned a = (t >= off) ? sb[t - off] : 0u;
        __syncthreads();
        sb[t] = u + a;
        __syncthreads();
    }
    unsigned ex = sb[t] - tot;     // exclusive
    bb[t] = ex;
    if (t == KC - 1) bb[KC] = (unsigned)E;
    unsigned run = ex;
    for (int b = 0; b < CB; ++b) {
        base[(size_t)b * KC + t] = run;                 // coalesced
        run += counts[(size_t)b * KC + t];
    }
}

__global__ __launch_bounds__(256)
void scatter_kernel(const int* __restrict__ ei0, const int* __restrict__ ei1,
                    const float* __restrict__ dw, const float* __restrict__ gea,
                    const unsigned* __restrict__ base,
                    uint4* __restrict__ rec, int E) {
    __shared__ unsigned cursor[KC];
    __shared__ unsigned h[KC];
    __shared__ unsigned tstart[KC];
    __shared__ unsigned sb[KC];
    __shared__ uint4 staged[TTILE];      // 32 KB
    int tid = threadIdx.x;
    cursor[tid] = base[(size_t)blockIdx.x * KC + tid];
    int chunk = (E + CB - 1) / CB;
    int lo = blockIdx.x * chunk;
    int hi = min(lo + chunk, E);
    __syncthreads();

    for (int tileLo = lo; tileLo < hi; tileLo += TTILE) {
        int tn = min(TTILE, hi - tileLo);
        h[tid] = 0;
        __syncthreads();

        unsigned k_r[EPT], w0_r[EPT], ge_r[EPT], cf_r[EPT], rk_r[EPT];
#pragma unroll
        for (int j = 0; j < EPT; ++j) {
            int off = j * 256 + tid;
            k_r[j] = 0xFFFFFFFFu;
            if (off < tn) {
                int i = tileLo + off;
                int s0 = ei0[i];
                int s1 = ei1[i];
                unsigned k = (unsigned)s0 >> S_LOG;
                k_r[j] = k;
                w0_r[j] = (unsigned)s1 | ((unsigned)(s0 & (SBUCKET - 1)) << 17);
                ge_r[j] = __float_as_uint(gea[i]);
                float sig = 1.0f / (1.0f + __expf(-dw[i]));
                cf_r[j] = __float_as_uint(sqrtf(sig));
            }
        }
#pragma unroll
        for (int j = 0; j < EPT; ++j)
            if (k_r[j] != 0xFFFFFFFFu) rk_r[j] = atomicAdd(&h[k_r[j]], 1u);
        __syncthreads();

        // exclusive scan of h -> tstart
        unsigned hv = h[tid];
        sb[tid] = hv;
        __syncthreads();
        for (int off = 1; off < KC; off <<= 1) {
            unsigned u = sb[tid];
            unsigned a = (tid >= off) ? sb[tid - off] : 0u;
            __syncthreads();
            sb[tid] = u + a;
            __syncthreads();
        }
        tstart[tid] = sb[tid] - hv;
        __syncthreads();

        // stage records bucket-sorted in LDS
#pragma unroll
        for (int j = 0; j < EPT; ++j)
            if (k_r[j] != 0xFFFFFFFFu) {
                unsigned slot = tstart[k_r[j]] + rk_r[j];
                staged[slot] = make_uint4(w0_r[j], ge_r[j], cf_r[j], k_r[j]);
            }
        __syncthreads();

        // coalesced write-out: consecutive i -> consecutive global pos within bucket runs
        for (int i = tid; i < tn; i += 256) {
            uint4 u = staged[i];
            unsigned k = u.w;
            unsigned pos = cursor[k] + ((unsigned)i - tstart[k]);
            rec[pos] = u;
        }
        __syncthreads();
        cursor[tid] += h[tid];
        __syncthreads();
    }
}

// partial degree per bucket slice: grid (K, MD)
__global__ __launch_bounds__(256)
void pdeg_kernel(const uint4* __restrict__ rec, const unsigned* __restrict__ bb,
                 float* __restrict__ pdeg, int Npad) {
    __shared__ float degl[SBUCKET];
    int k = blockIdx.x, m = blockIdx.y, tid = threadIdx.x;
    for (int i = tid; i < SBUCKET; i += 256) degl[i] = 0.0f;
    unsigned lo = bb[k], hi = bb[k + 1];
    unsigned cnt = hi - lo;
    unsigned slice = (cnt + MD - 1) / MD;
    unsigned slo = lo + m * slice;
    unsigned shi = min(slo + slice, hi);
    __syncthreads();
    for (unsigned r = slo + tid; r < shi; r += 256) {
        uint4 u = rec[r];
        atomicAdd(&degl[u.x >> 17], __uint_as_float(u.y));
    }
    __syncthreads();
    for (int i = tid; i < SBUCKET; i += 256)
        pdeg[(size_t)m * Npad + ((size_t)k << S_LOG) + i] = degl[i];
}

// main accumulation: grid (K, MA), no global atomics
__global__ __launch_bounds__(256)
void accum_kernel(const uint4* __restrict__ rec, const unsigned* __restrict__ bb,
                  const float* __restrict__ pdeg, const float* __restrict__ yT,
                  float* __restrict__ pout, int N, int Npad) {
    __shared__ float invd2[SBUCKET];
    __shared__ float y0l[BATCH][SBUCKET];
    __shared__ float outl[BATCH][SBUCKET];
    int k = blockIdx.x, m = blockIdx.y, tid = threadIdx.x;
    int n0 = k << S_LOG;

    for (int i = tid; i < SBUCKET; i += 256) {
        float d = 0.0f;
#pragma unroll
        for (int md = 0; md < MD; ++md)
            d += pdeg[(size_t)md * Npad + (size_t)n0 + i];
        invd2[i] = 1.0f / (d * d);
    }
    for (int i = tid; i < BATCH * SBUCKET; i += 256) ((float*)outl)[i] = 0.0f;
    int nvalid = min(SBUCKET, N - n0);
    for (int i = tid; i < nvalid * BATCH; i += 256) {
        int j = i >> 3, b = i & 7;
        y0l[b][j] = yT[(size_t)n0 * BATCH + i];
    }
    unsigned lo = bb[k], hi = bb[k + 1];
    unsigned cnt = hi - lo;
    unsigned slice = (cnt + MA - 1) / MA;
    unsigned slo = lo + m * slice;
    unsigned shi = min(slo + slice, hi);
    __syncthreads();

    const float4* yt4 = (const float4*)yT;
    for (unsigned r = slo + tid; r < shi; r += 256) {
        uint4 u = rec[r];
        unsigned s1 = u.x & 0x1FFFFu;
        unsigned s0l = u.x >> 17;
        float c = __uint_as_float(u.z) * invd2[s0l];
        float4 ya = yt4[2 * (size_t)s1];
        float4 yb = yt4[2 * (size_t)s1 + 1];
        float y1v[BATCH] = {ya.x, ya.y, ya.z, ya.w, yb.x, yb.y, yb.z, yb.w};
#pragma unroll
        for (int b = 0; b < BATCH; ++b) {
            float gm = c * fmaxf(y0l[b][s0l] - y1v[b], 0.0f);
            if (gm != 0.0f) atomicAdd(&outl[b][s0l], gm);
        }
    }
    __syncthreads();

    for (int i = tid; i < BATCH * SBUCKET; i += 256) {
        int b = i >> S_LOG;
        int j = i & (SBUCKET - 1);
        pout[((size_t)m * BATCH + b) * Npad + n0 + j] = outl[b][j];
    }
}

// out = 1 - sum_m pout : grid ((N+255)/256, BATCH)
__global__ void finalize_kernel(const float* __restrict__ pout,
                                float* __restrict__ out, int N, int Npad) {
    int n = blockIdx.x * blockDim.x + threadIdx.x;
    int b = blockIdx.y;
    if (n < N) {
        float s = 0.0f;
#pragma unroll
        for (int m = 0; m < MA; ++m)
            s += pout[((size_t)m * BATCH + b) * Npad + n];
        out[(size_t)b * N + n] = 1.0f - s;
    }
}

// ---------------- fallback (R1 path) ----------------

__global__ void fill_one_kernel(float* __restrict__ out, int n) {
    int i = blockIdx.x * blockDim.x + threadIdx.x;
    if (i < n) out[i] = 1.0f;
}

__global__ void deg_kernel(const float* __restrict__ gea,
                           const int* __restrict__ ei0,
                           float* __restrict__ deg, int E) {
    int e = blockIdx.x * blockDim.x + threadIdx.x;
    if (e < E) atomicAdd(&deg[ei0[e]], gea[e]);
}

__global__ void edge_kernel(const float* __restrict__ y,
                            const float* __restrict__ dw,
                            const int* __restrict__ ei0,
                            const int* __restrict__ ei1,
                            const float* __restrict__ deg,
                            float* __restrict__ out,
                            int E, int N) {
    int e = blockIdx.x * blockDim.x + threadIdx.x;
    if (e >= E) return;
    int s0 = ei0[e];
    int s1 = ei1[e];
    float d = deg[s0];
    float inv = 1.0f / (d * d);
    float sig = 1.0f / (1.0f + __expf(-dw[e]));
    float coef = sqrtf(sig) * inv;
#pragma unroll
    for (int b = 0; b < BATCH; ++b) {
        float y0 = y[(size_t)b * N + s0];
        float y1 = y[(size_t)b * N + s1];
        float gm = coef * fmaxf(y0 - y1, 0.0f);
        if (gm != 0.0f) atomicAdd(&out[(size_t)b * N + s0], -gm);
    }
}

// ---------------- launch ----------------

extern "C" void kernel_launch(void* const* d_in, const int* in_sizes, int n_in,
                              void* d_out, int out_size, void* d_ws, size_t ws_size,
                              hipStream_t stream) {
    const float* y   = (const float*)d_in[0];   // [B,N]
    const float* gea = (const float*)d_in[2];   // [E]
    const float* dw  = (const float*)d_in[3];   // [E]
    const int*   ei  = (const int*)d_in[4];     // [2,E]

    const int E = in_sizes[2];
    const int N = in_sizes[0] / BATCH;
    const int* ei0 = ei;
    const int* ei1 = ei + E;

    const int K = (N + SBUCKET - 1) >> S_LOG;
    const int Npad = K << S_LOG;

    size_t o_yT     = 0;
    size_t o_rec    = o_yT     + alignup((size_t)N * BATCH * 4);
    size_t o_counts = o_rec    + alignup((size_t)E * 16);
    size_t o_base   = o_counts + alignup((size_t)CB * KC * 4);
    size_t o_bb     = o_base   + alignup((size_t)CB * KC * 4);
    size_t o_pdeg   = o_bb     + alignup((size_t)(KC + 1) * 4);
    size_t o_pout   = o_pdeg   + alignup((size_t)MD * Npad * 4);
    size_t need     = o_pout   + alignup((size_t)MA * BATCH * Npad * 4);

    if (K <= KC && N <= 131071 && ws_size >= need) {
        char* w = (char*)d_ws;
        float*    yT     = (float*)(w + o_yT);
        uint4*    rec    = (uint4*)(w + o_rec);
        unsigned* counts = (unsigned*)(w + o_counts);
        unsigned* base   = (unsigned*)(w + o_base);
        unsigned* bb     = (unsigned*)(w + o_bb);
        float*    pdeg   = (float*)(w + o_pdeg);
        float*    pout   = (float*)(w + o_pout);

        transpose_y<<<(N + 255) / 256, 256, 0, stream>>>(y, yT, N);
        count_kernel<<<CB, 256, 0, stream>>>(ei0, counts, E);
        scan_kernel<<<1, 256, 0, stream>>>(counts, base, bb, E);
        scatter_kernel<<<CB, 256, 0, stream>>>(ei0, ei1, dw, gea, base, rec, E);
        pdeg_kernel<<<dim3(K, MD), 256, 0, stream>>>(rec, bb, pdeg, Npad);
        accum_kernel<<<dim3(K, MA), 256, 0, stream>>>(rec, bb, pdeg, yT,
                                                      pout, N, Npad);
        finalize_kernel<<<dim3((N + 255) / 256, BATCH), 256, 0, stream>>>(
            pout, (float*)d_out, N, Npad);
    } else {
        float* deg = (float*)d_ws;
        hipMemsetAsync(deg, 0, (size_t)N * sizeof(float), stream);
        fill_one_kernel<<<(out_size + 255) / 256, 256, 0, stream>>>((float*)d_out, out_size);
        deg_kernel<<<(E + 255) / 256, 256, 0, stream>>>(gea, ei0, deg, E);
        edge_kernel<<<(E + 255) / 256, 256, 0, stream>>>(y, dw, ei0, ei1, deg,
                                                         (float*)d_out, E, N);
    }
}

// Round 4
// 277.602 us; speedup vs baseline: 3.1893x; 1.0083x over previous
//
#include <hip/hip_runtime.h>

#define BATCH 8
#define S_LOG 9
#define SBUCKET 512          // nodes per bucket
#define KC 256               // max buckets (N <= 131071)
#define CB 512               // blocks for count/scatter
#define TTILE 2048           // edges per sort tile
#define EPT (TTILE / 256)    // edges per thread per tile
#define MD 8                 // deg sub-blocks per bucket
#define MA 8                 // accum sub-blocks per bucket

static inline size_t alignup(size_t x) { return (x + 255) & ~(size_t)255; }

// ---------------- pipeline kernels ----------------

__global__ void transpose_y(const float* __restrict__ y, float* __restrict__ yT, int N) {
    int n = blockIdx.x * blockDim.x + threadIdx.x;
    if (n < N) {
        float v[BATCH];
#pragma unroll
        for (int b = 0; b < BATCH; ++b) v[b] = y[(size_t)b * N + n];
        float4* dst = (float4*)(yT + (size_t)n * BATCH);
        dst[0] = make_float4(v[0], v[1], v[2], v[3]);
        dst[1] = make_float4(v[4], v[5], v[6], v[7]);
    }
}

__global__ void count_kernel(const int* __restrict__ ei0,
                             unsigned* __restrict__ counts, int E) {
    __shared__ unsigned cnt[KC];
    int tid = threadIdx.x;
    cnt[tid] = 0;
    __syncthreads();
    int chunk = (E + CB - 1) / CB;
    int lo = blockIdx.x * chunk;
    int hi = min(lo + chunk, E);
    for (int i = lo + tid; i < hi; i += 256)
        atomicAdd(&cnt[ei0[i] >> S_LOG], 1u);
    __syncthreads();
    counts[(size_t)blockIdx.x * KC + tid] = cnt[tid];   // coalesced
}

// one block, 256 threads: thread t owns bucket t
__global__ void scan_kernel(const unsigned* __restrict__ counts,
                            unsigned* __restrict__ base,
                            unsigned* __restrict__ bb, int E) {
    __shared__ unsigned sb[KC];
    int t = threadIdx.x;
    unsigned tot = 0;
    for (int b = 0; b < CB; ++b) tot += counts[(size_t)b * KC + t];  // coalesced
    sb[t] = tot;
    __syncthreads();
    for (int off = 1; off < KC; off <<= 1) {
        unsigned u = sb[t];
        unsigned a = (t >= off) ? sb[t - off] : 0u;
        __syncthreads();
        sb[t] = u + a;
        __syncthreads();
    }
    unsigned ex = sb[t] - tot;     // exclusive
    bb[t] = ex;
    if (t == KC - 1) bb[KC] = (unsigned)E;
    unsigned run = ex;
    for (int b = 0; b < CB; ++b) {
        base[(size_t)b * KC + t] = run;                 // coalesced
        run += counts[(size_t)b * KC + t];
    }
}

__global__ __launch_bounds__(256)
void scatter_kernel(const int* __restrict__ ei0, const int* __restrict__ ei1,
                    const float* __restrict__ dw, const float* __restrict__ gea,
                    const unsigned* __restrict__ base,
                    uint2* __restrict__ w0gea, uint2* __restrict__ w0coef, int E) {
    __shared__ unsigned cursor[KC];
    __shared__ unsigned h[KC];
    __shared__ unsigned tstart[KC];
    __shared__ unsigned sb[KC];
    __shared__ uint4 staged[TTILE];      // 32 KB
    int tid = threadIdx.x;
    cursor[tid] = base[(size_t)blockIdx.x * KC + tid];
    int chunk = (E + CB - 1) / CB;
    int lo = blockIdx.x * chunk;
    int hi = min(lo + chunk, E);
    __syncthreads();

    for (int tileLo = lo; tileLo < hi; tileLo += TTILE) {
        int tn = min(TTILE, hi - tileLo);
        h[tid] = 0;
        __syncthreads();

        unsigned k_r[EPT], w0_r[EPT], ge_r[EPT], cf_r[EPT], rk_r[EPT];
#pragma unroll
        for (int j = 0; j < EPT; ++j) {
            int off = j * 256 + tid;
            k_r[j] = 0xFFFFFFFFu;
            if (off < tn) {
                int i = tileLo + off;
                int s0 = ei0[i];
                int s1 = ei1[i];
                unsigned k = (unsigned)s0 >> S_LOG;
                k_r[j] = k;
                w0_r[j] = (unsigned)s1 | ((unsigned)(s0 & (SBUCKET - 1)) << 17);
                ge_r[j] = __float_as_uint(gea[i]);
                float sig = 1.0f / (1.0f + __expf(-dw[i]));
                cf_r[j] = __float_as_uint(sqrtf(sig));
            }
        }
#pragma unroll
        for (int j = 0; j < EPT; ++j)
            if (k_r[j] != 0xFFFFFFFFu) rk_r[j] = atomicAdd(&h[k_r[j]], 1u);
        __syncthreads();

        unsigned hv = h[tid];
        sb[tid] = hv;
        __syncthreads();
        for (int off = 1; off < KC; off <<= 1) {
            unsigned u = sb[tid];
            unsigned a = (tid >= off) ? sb[tid - off] : 0u;
            __syncthreads();
            sb[tid] = u + a;
            __syncthreads();
        }
        tstart[tid] = sb[tid] - hv;
        __syncthreads();

#pragma unroll
        for (int j = 0; j < EPT; ++j)
            if (k_r[j] != 0xFFFFFFFFu) {
                unsigned slot = tstart[k_r[j]] + rk_r[j];
                staged[slot] = make_uint4(w0_r[j], ge_r[j], cf_r[j], k_r[j]);
            }
        __syncthreads();

        // coalesced write-out: consecutive i -> consecutive global pos within bucket runs
        for (int i = tid; i < tn; i += 256) {
            uint4 u = staged[i];
            unsigned k = u.w;
            unsigned pos = cursor[k] + ((unsigned)i - tstart[k]);
            w0gea[pos]  = make_uint2(u.x, u.y);
            w0coef[pos] = make_uint2(u.x, u.z);
        }
        __syncthreads();
        cursor[tid] += h[tid];
        __syncthreads();
    }
}

// partial degree per bucket slice: grid (K, MD)
__global__ __launch_bounds__(256)
void pdeg_kernel(const uint2* __restrict__ w0gea, const unsigned* __restrict__ bb,
                 float* __restrict__ pdeg, int Npad) {
    __shared__ float degl[SBUCKET];
    int k = blockIdx.x, m = blockIdx.y, tid = threadIdx.x;
    for (int i = tid; i < SBUCKET; i += 256) degl[i] = 0.0f;
    unsigned lo = bb[k], hi = bb[k + 1];
    unsigned cnt = hi - lo;
    unsigned slice = (cnt + MD - 1) / MD;
    unsigned slo = lo + m * slice;
    unsigned shi = min(slo + slice, hi);
    __syncthreads();
    unsigned r = slo + tid;
    uint2 nxt;
    if (r < shi) nxt = w0gea[r];
    for (; r < shi; r += 256) {
        uint2 cur = nxt;
        unsigned rn = r + 256;
        if (rn < shi) nxt = w0gea[rn];
        atomicAdd(&degl[cur.x >> 17], __uint_as_float(cur.y));
    }
    __syncthreads();
    for (int i = tid; i < SBUCKET; i += 256)
        pdeg[(size_t)m * Npad + ((size_t)k << S_LOG) + i] = degl[i];
}

// main accumulation: grid (K, MA, 2) — each z-half handles 4 batches
__global__ __launch_bounds__(256)
void accum_kernel(const uint2* __restrict__ w0coef, const unsigned* __restrict__ bb,
                  const float* __restrict__ pdeg, const float* __restrict__ yT,
                  float* __restrict__ pout, int N, int Npad) {
    __shared__ float invd2[SBUCKET];
    __shared__ float y0l[4][SBUCKET];
    __shared__ float outl[4][SBUCKET];
    int k = blockIdx.x, m = blockIdx.y, tid = threadIdx.x;
    int b0 = blockIdx.z * 4;
    int n0 = k << S_LOG;

    for (int i = tid; i < SBUCKET; i += 256) {
        float d = 0.0f;
#pragma unroll
        for (int md = 0; md < MD; ++md)
            d += pdeg[(size_t)md * Npad + (size_t)n0 + i];
        invd2[i] = 1.0f / (d * d);
    }
    for (int i = tid; i < 4 * SBUCKET; i += 256) ((float*)outl)[i] = 0.0f;
    int nvalid = min(SBUCKET, N - n0);
    for (int j = tid; j < nvalid; j += 256) {
        float4 v = *(const float4*)(yT + ((size_t)(n0 + j)) * BATCH + b0);
        y0l[0][j] = v.x; y0l[1][j] = v.y; y0l[2][j] = v.z; y0l[3][j] = v.w;
    }
    unsigned lo = bb[k], hi = bb[k + 1];
    unsigned cnt = hi - lo;
    unsigned slice = (cnt + MA - 1) / MA;
    unsigned slo = lo + m * slice;
    unsigned shi = min(slo + slice, hi);
    __syncthreads();

    unsigned r = slo + tid;
    uint2 nxt;
    if (r < shi) nxt = w0coef[r];
    for (; r < shi; r += 256) {
        uint2 cur = nxt;
        unsigned rn = r + 256;
        if (rn < shi) nxt = w0coef[rn];           // prefetch next record
        unsigned s1 = cur.x & 0x1FFFFu;
        unsigned s0l = cur.x >> 17;
        float4 yv = *(const float4*)(yT + (size_t)s1 * BATCH + b0);
        float c = __uint_as_float(cur.y) * invd2[s0l];
        float gm0 = c * fmaxf(y0l[0][s0l] - yv.x, 0.0f);
        float gm1 = c * fmaxf(y0l[1][s0l] - yv.y, 0.0f);
        float gm2 = c * fmaxf(y0l[2][s0l] - yv.z, 0.0f);
        float gm3 = c * fmaxf(y0l[3][s0l] - yv.w, 0.0f);
        if (gm0 != 0.0f) atomicAdd(&outl[0][s0l], gm0);
        if (gm1 != 0.0f) atomicAdd(&outl[1][s0l], gm1);
        if (gm2 != 0.0f) atomicAdd(&outl[2][s0l], gm2);
        if (gm3 != 0.0f) atomicAdd(&outl[3][s0l], gm3);
    }
    __syncthreads();

    for (int i = tid; i < 4 * SBUCKET; i += 256) {
        int b = i >> S_LOG;
        int j = i & (SBUCKET - 1);
        pout[((size_t)m * BATCH + b0 + b) * Npad + n0 + j] = outl[b][j];
    }
}

// out = 1 - sum_m pout : grid ((N+255)/256, BATCH)
__global__ void finalize_kernel(const float* __restrict__ pout,
                                float* __restrict__ out, int N, int Npad) {
    int n = blockIdx.x * blockDim.x + threadIdx.x;
    int b = blockIdx.y;
    if (n < N) {
        float s = 0.0f;
#pragma unroll
        for (int m = 0; m < MA; ++m)
            s += pout[((size_t)m * BATCH + b) * Npad + n];
        out[(size_t)b * N + n] = 1.0f - s;
    }
}

// ---------------- fallback (R1 path) ----------------

__global__ void fill_one_kernel(float* __restrict__ out, int n) {
    int i = blockIdx.x * blockDim.x + threadIdx.x;
    if (i < n) out[i] = 1.0f;
}

__global__ void deg_kernel(const float* __restrict__ gea,
                           const int* __restrict__ ei0,
                           float* __restrict__ deg, int E) {
    int e = blockIdx.x * blockDim.x + threadIdx.x;
    if (e < E) atomicAdd(&deg[ei0[e]], gea[e]);
}

__global__ void edge_kernel(const float* __restrict__ y,
                            const float* __restrict__ dw,
                            const int* __restrict__ ei0,
                            const int* __restrict__ ei1,
                            const float* __restrict__ deg,
                            float* __restrict__ out,
                            int E, int N) {
    int e = blockIdx.x * blockDim.x + threadIdx.x;
    if (e >= E) return;
    int s0 = ei0[e];
    int s1 = ei1[e];
    float d = deg[s0];
    float inv = 1.0f / (d * d);
    float sig = 1.0f / (1.0f + __expf(-dw[e]));
    float coef = sqrtf(sig) * inv;
#pragma unroll
    for (int b = 0; b < BATCH; ++b) {
        float y0 = y[(size_t)b * N + s0];
        float y1 = y[(size_t)b * N + s1];
        float gm = coef * fmaxf(y0 - y1, 0.0f);
        if (gm != 0.0f) atomicAdd(&out[(size_t)b * N + s0], -gm);
    }
}

// ---------------- launch ----------------

extern "C" void kernel_launch(void* const* d_in, const int* in_sizes, int n_in,
                              void* d_out, int out_size, void* d_ws, size_t ws_size,
                              hipStream_t stream) {
    const float* y   = (const float*)d_in[0];   // [B,N]
    const float* gea = (const float*)d_in[2];   // [E]
    const float* dw  = (const float*)d_in[3];   // [E]
    const int*   ei  = (const int*)d_in[4];     // [2,E]

    const int E = in_sizes[2];
    const int N = in_sizes[0] / BATCH;
    const int* ei0 = ei;
    const int* ei1 = ei + E;

    const int K = (N + SBUCKET - 1) >> S_LOG;
    const int Npad = K << S_LOG;

    size_t o_yT     = 0;
    size_t o_rga    = o_yT     + alignup((size_t)N * BATCH * 4);
    size_t o_rcf    = o_rga    + alignup((size_t)E * 8);
    size_t o_counts = o_rcf    + alignup((size_t)E * 8);
    size_t o_base   = o_counts + alignup((size_t)CB * KC * 4);
    size_t o_bb     = o_base   + alignup((size_t)CB * KC * 4);
    size_t o_pdeg   = o_bb     + alignup((size_t)(KC + 1) * 4);
    size_t o_pout   = o_pdeg   + alignup((size_t)MD * Npad * 4);
    size_t need     = o_pout   + alignup((size_t)MA * BATCH * Npad * 4);

    if (K <= KC && N <= 131071 && ws_size >= need) {
        char* w = (char*)d_ws;
        float*    yT     = (float*)(w + o_yT);
        uint2*    w0gea  = (uint2*)(w + o_rga);
        uint2*    w0coef = (uint2*)(w + o_rcf);
        unsigned* counts = (unsigned*)(w + o_counts);
        unsigned* base   = (unsigned*)(w + o_base);
        unsigned* bb     = (unsigned*)(w + o_bb);
        float*    pdeg   = (float*)(w + o_pdeg);
        float*    pout   = (float*)(w + o_pout);

        transpose_y<<<(N + 255) / 256, 256, 0, stream>>>(y, yT, N);
        count_kernel<<<CB, 256, 0, stream>>>(ei0, counts, E);
        scan_kernel<<<1, 256, 0, stream>>>(counts, base, bb, E);
        scatter_kernel<<<CB, 256, 0, stream>>>(ei0, ei1, dw, gea, base,
                                               w0gea, w0coef, E);
        pdeg_kernel<<<dim3(K, MD), 256, 0, stream>>>(w0gea, bb, pdeg, Npad);
        accum_kernel<<<dim3(K, MA, 2), 256, 0, stream>>>(w0coef, bb, pdeg, yT,
                                                         pout, N, Npad);
        finalize_kernel<<<dim3((N + 255) / 256, BATCH), 256, 0, stream>>>(
            pout, (float*)d_out, N, Npad);
    } else {
        float* deg = (float*)d_ws;
        hipMemsetAsync(deg, 0, (size_t)N * sizeof(float), stream);
        fill_one_kernel<<<(out_size + 255) / 256, 256, 0, stream>>>((float*)d_out, out_size);
        deg_kernel<<<(E + 255) / 256, 256, 0, stream>>>(gea, ei0, deg, E);
        edge_kernel<<<(E + 255) / 256, 256, 0, stream>>>(y, dw, ei0, ei1, deg,
                                                         (float*)d_out, E, N);
    }
}